// Round 3
// baseline (262.773 us; speedup 1.0000x reference)
//
#include <hip/hip_runtime.h>
#include <math.h>

#define Bb 4
#define Rr 4
#define Nn 256
#define Ee 64
#define LAMDA 0.5f
#define EPSf 1e-6f

// ---------------- K1: Q = n_emb @ Wq.T, K = n_emb @ Wk.T ----------------
__global__ __launch_bounds__(64) void qk_proj(
    const float* __restrict__ n_emb, const float* __restrict__ Wq,
    const float* __restrict__ Wk, float* __restrict__ Qo, float* __restrict__ Ko)
{
    int bn = blockIdx.x;        // b*N + n
    int e  = threadIdx.x;       // 0..63
    __shared__ float nrow[Ee];
    nrow[e] = n_emb[bn * Ee + e];
    __syncthreads();
    const float* wq = Wq + e * Ee;
    const float* wk = Wk + e * Ee;
    float q = 0.f, k = 0.f;
#pragma unroll
    for (int f = 0; f < Ee; ++f) {
        float nv = nrow[f];
        q += nv * wq[f];
        k += nv * wk[f];
    }
    Qo[bn * Ee + e] = q;
    Ko[bn * Ee + e] = k;
}

// ---------------- K2: ori[b,q,k] = dot(Q[b,q], K[b,k]) / 4096 ----------------
__global__ __launch_bounds__(256) void ori_kernel(
    const float* __restrict__ Q, const float* __restrict__ K,
    float* __restrict__ ori)
{
    int b = blockIdx.x / Nn;
    int q = blockIdx.x % Nn;
    int k = threadIdx.x;        // 0..255
    __shared__ float4 qs[Ee / 4];
    if (k < Ee / 4) qs[k] = ((const float4*)(Q + (b * Nn + q) * Ee))[k];
    __syncthreads();
    const float4* kp = (const float4*)(K + (b * Nn + k) * Ee);
    float acc = 0.f;
#pragma unroll
    for (int u = 0; u < Ee / 4; ++u) {
        float4 kv = kp[u];
        float4 qv = qs[u];
        acc += qv.x * kv.x + qv.y * kv.y + qv.z * kv.z + qv.w * kv.w;
    }
    ori[(b * Nn + q) * Nn + k] = acc * (1.0f / 4096.0f);
}

// ---------------- block-wide sum over 256 threads ----------------
__device__ __forceinline__ float block_sum256(float v, float* s_red) {
#pragma unroll
    for (int m = 32; m >= 1; m >>= 1) v += __shfl_xor(v, m);
    int wid  = threadIdx.x >> 6;
    int lane = threadIdx.x & 63;
    if (lane == 0) s_red[wid] = v;
    __syncthreads();
    float tot = s_red[0] + s_red[1] + s_red[2] + s_red[3];
    __syncthreads();
    return tot;
}

// ---------------- K3: the heavy fused kernel ----------------
// One block per (b, r, i) row: 4096 blocks x 256 threads.
// Phase 1: 16 INDEPENDENT iterations (no cross-lane ops inside the loop):
// at step v, thread t reads float4 #(v*256 + t) — wave covers 1 KB
// contiguous per instruction — and accumulates the squared sum into its
// own register accv[v]. All shfl reductions happen AFTER the loop, so the
// compiler can keep many load-triples in flight (ILP latency hiding).
__global__ __launch_bounds__(256, 4) void raa_kernel(
    const float* __restrict__ h_adj, const float* __restrict__ r_adj,
    const float* __restrict__ t_adj, const float* __restrict__ mask_r,
    const float* __restrict__ mask_u, const float* __restrict__ ori,
    float* __restrict__ out)
{
    const int blk = blockIdx.x;            // (b*R + r)*N + i
    const int b   = blk / (Rr * Nn);
    const int i   = blk % Nn;
    const int t   = threadIdx.x;

    const int rowbase4 = blk * (Nn * Ee / 4);   // float4 index, < 2^24
    const float4* __restrict__ hp = (const float4*)h_adj + rowbase4;
    const float4* __restrict__ rp = (const float4*)r_adj + rowbase4;
    const float4* __restrict__ tp = (const float4*)t_adj + rowbase4;

    // Hoist phase-2 loads: independent of phase 1, latency hides under it.
    const int j     = t;
    const int mbase = blk * Nn;
    const float mr  = mask_r[mbase + j];
    const float mu  = mask_u[mbase + j];
    const float o   = ori[(b * Nn + i) * Nn + j];

    __shared__ float s_pla[Nn];
    __shared__ float s_red[4];

    // Phase 1a: independent load + square-accumulate
    float accv[16];
#pragma unroll
    for (int v = 0; v < 16; ++v) {
        int idx = v * 256 + t;
        float4 hv = hp[idx];
        float4 rv = rp[idx];
        float4 tv = tp[idx];
        float dx = hv.x + rv.x - tv.x;
        float dy = hv.y + rv.y - tv.y;
        float dz = hv.z + rv.z - tv.z;
        float dw = hv.w + rv.w - tv.w;
        accv[v] = dx * dx + dy * dy + dz * dz + dw * dw;
    }

    // Phase 1b: 16-lane reduce per step, write pla score for column
    // jcol = v*16 + (t>>4)
#pragma unroll
    for (int v = 0; v < 16; ++v) {
        float a = accv[v];
        a += __shfl_xor(a, 1);
        a += __shfl_xor(a, 2);
        a += __shfl_xor(a, 4);
        a += __shfl_xor(a, 8);
        if ((t & 15) == 0) s_pla[v * 16 + (t >> 4)] = sqrtf(a);
    }
    __syncthreads();

    // Phase 2: masked softmax-ish chain, thread j owns column j
    float e1 = expf(-s_pla[j]) * mr;
    float s1 = block_sum256(e1, s_red);
    float w  = e1 / (s1 + EPSf);

    float raa = o * (1.0f + LAMDA * w);

    float e2 = expf(raa) * mu;
    float s2 = block_sum256(e2, s_red);

    out[mbase + j] = e2 / (s2 + EPSf);
}

extern "C" void kernel_launch(void* const* d_in, const int* in_sizes, int n_in,
                              void* d_out, int out_size, void* d_ws, size_t ws_size,
                              hipStream_t stream) {
    const float* n_emb  = (const float*)d_in[0];
    const float* h_adj  = (const float*)d_in[1];
    const float* r_adj  = (const float*)d_in[2];
    const float* t_adj  = (const float*)d_in[3];
    const float* mask_r = (const float*)d_in[4];
    const float* mask_u = (const float*)d_in[5];
    const float* Wq     = (const float*)d_in[6];
    const float* Wk     = (const float*)d_in[7];
    float* out = (float*)d_out;

    float* ws  = (float*)d_ws;
    float* Qw  = ws;                        // B*N*E = 65536 floats
    float* Kw  = ws + Bb * Nn * Ee;         // 65536 floats
    float* ori = ws + 2 * Bb * Nn * Ee;     // B*N*N = 262144 floats

    qk_proj<<<Bb * Nn, 64, 0, stream>>>(n_emb, Wq, Wk, Qw, Kw);
    ori_kernel<<<Bb * Nn, 256, 0, stream>>>(Qw, Kw, ori);
    raa_kernel<<<Bb * Rr * Nn, 256, 0, stream>>>(h_adj, r_adj, t_adj,
                                                 mask_r, mask_u, ori, out);
}

// Round 4
// 170.940 us; speedup vs baseline: 1.5372x; 1.5372x over previous
//
#include <hip/hip_runtime.h>
#include <math.h>

#define Bb 4
#define Rr 4
#define Nn 256
#define Ee 64
#define LAMDA 0.5f
#define EPSf 1e-6f

// ---------------- K1: Q = n_emb @ Wq.T, K = n_emb @ Wk.T ----------------
__global__ __launch_bounds__(64) void qk_proj(
    const float* __restrict__ n_emb, const float* __restrict__ Wq,
    const float* __restrict__ Wk, float* __restrict__ Qo, float* __restrict__ Ko)
{
    int bn = blockIdx.x;        // b*N + n
    int e  = threadIdx.x;       // 0..63
    __shared__ float nrow[Ee];
    nrow[e] = n_emb[bn * Ee + e];
    __syncthreads();
    const float* wq = Wq + e * Ee;
    const float* wk = Wk + e * Ee;
    float q = 0.f, k = 0.f;
#pragma unroll
    for (int f = 0; f < Ee; ++f) {
        float nv = nrow[f];
        q += nv * wq[f];
        k += nv * wk[f];
    }
    Qo[bn * Ee + e] = q;
    Ko[bn * Ee + e] = k;
}

// ---------------- K2: ori[b,q,k] = dot(Q[b,q], K[b,k]) / 4096 ----------------
__global__ __launch_bounds__(256) void ori_kernel(
    const float* __restrict__ Q, const float* __restrict__ K,
    float* __restrict__ ori)
{
    int b = blockIdx.x / Nn;
    int q = blockIdx.x % Nn;
    int k = threadIdx.x;        // 0..255
    __shared__ float4 qs[Ee / 4];
    if (k < Ee / 4) qs[k] = ((const float4*)(Q + (b * Nn + q) * Ee))[k];
    __syncthreads();
    const float4* kp = (const float4*)(K + (b * Nn + k) * Ee);
    float acc = 0.f;
#pragma unroll
    for (int u = 0; u < Ee / 4; ++u) {
        float4 kv = kp[u];
        float4 qv = qs[u];
        acc += qv.x * kv.x + qv.y * kv.y + qv.z * kv.z + qv.w * kv.w;
    }
    ori[(b * Nn + q) * Nn + k] = acc * (1.0f / 4096.0f);
}

// ---------------- block-wide sum over 256 threads ----------------
__device__ __forceinline__ float block_sum256(float v, float* s_red) {
#pragma unroll
    for (int m = 32; m >= 1; m >>= 1) v += __shfl_xor(v, m);
    int wid  = threadIdx.x >> 6;
    int lane = threadIdx.x & 63;
    if (lane == 0) s_red[wid] = v;
    __syncthreads();
    float tot = s_red[0] + s_red[1] + s_red[2] + s_red[3];
    __syncthreads();
    return tot;
}

// ---------------- K3: the heavy fused kernel ----------------
// One block per (b, r, i) row: 4096 blocks x 256 threads.
// Phase 1 is a 2-deep software pipeline over 4 groups of 4 coalesced
// float4-triple loads: issue group g+1's 12 loads (48 VGPRs), then compute
// + 16-lane-shfl-reduce group g (its 48 VGPRs die as they're consumed).
// Peak liveness ~110 VGPRs -> fits the 128 cap of launch_bounds(256,4)
// with NO scratch spill (R3's failure mode: 16 groups live = 192 regs).
// All parity/group indices are compile-time (full unroll) so the float4
// arrays stay in registers (no runtime-indexed ext_vector -> scratch).
__global__ __launch_bounds__(256, 4) void raa_kernel(
    const float* __restrict__ h_adj, const float* __restrict__ r_adj,
    const float* __restrict__ t_adj, const float* __restrict__ mask_r,
    const float* __restrict__ mask_u, const float* __restrict__ ori,
    float* __restrict__ out)
{
    const int blk = blockIdx.x;            // (b*R + r)*N + i
    const int b   = blk / (Rr * Nn);
    const int i   = blk % Nn;
    const int t   = threadIdx.x;

    const int rowbase4 = blk * (Nn * Ee / 4);   // float4 index, < 2^24
    const float4* __restrict__ hp = (const float4*)h_adj + rowbase4;
    const float4* __restrict__ rp = (const float4*)r_adj + rowbase4;
    const float4* __restrict__ tp = (const float4*)t_adj + rowbase4;

    // Hoist phase-2 loads: independent of phase 1, latency hides under it.
    const int j     = t;
    const int mbase = blk * Nn;
    const float mr  = mask_r[mbase + j];
    const float mu  = mask_u[mbase + j];
    const float o   = ori[(b * Nn + i) * Nn + j];

    __shared__ float s_pla[Nn];
    __shared__ float s_red[4];

    float4 ha[2][4], ra[2][4], ta[2][4];

    // Prologue: load group 0 into parity 0
#pragma unroll
    for (int u = 0; u < 4; ++u) {
        int idx = u * 256 + t;
        ha[0][u] = hp[idx];
        ra[0][u] = rp[idx];
        ta[0][u] = tp[idx];
    }

#pragma unroll
    for (int g = 0; g < 4; ++g) {
        const int p = g & 1;
        const int q = p ^ 1;
        // Issue next group's loads BEFORE consuming this group's regs.
        if (g < 3) {
#pragma unroll
            for (int u = 0; u < 4; ++u) {
                int idx = ((g + 1) * 4 + u) * 256 + t;
                ha[q][u] = hp[idx];
                ra[q][u] = rp[idx];
                ta[q][u] = tp[idx];
            }
        }
        // Compute + reduce group g (steps v = 4g..4g+3)
#pragma unroll
        for (int u = 0; u < 4; ++u) {
            float4 hv = ha[p][u];
            float4 rv = ra[p][u];
            float4 tv = ta[p][u];
            float dx = hv.x + rv.x - tv.x;
            float dy = hv.y + rv.y - tv.y;
            float dz = hv.z + rv.z - tv.z;
            float dw = hv.w + rv.w - tv.w;
            float a  = dx * dx + dy * dy + dz * dz + dw * dw;
            a += __shfl_xor(a, 1);
            a += __shfl_xor(a, 2);
            a += __shfl_xor(a, 4);
            a += __shfl_xor(a, 8);
            if ((t & 15) == 0) s_pla[(g * 4 + u) * 16 + (t >> 4)] = sqrtf(a);
        }
    }
    __syncthreads();

    // Phase 2: masked softmax-ish chain, thread j owns column j
    float e1 = expf(-s_pla[j]) * mr;
    float s1 = block_sum256(e1, s_red);
    float w  = e1 / (s1 + EPSf);

    float raa = o * (1.0f + LAMDA * w);

    float e2 = expf(raa) * mu;
    float s2 = block_sum256(e2, s_red);

    out[mbase + j] = e2 / (s2 + EPSf);
}

extern "C" void kernel_launch(void* const* d_in, const int* in_sizes, int n_in,
                              void* d_out, int out_size, void* d_ws, size_t ws_size,
                              hipStream_t stream) {
    const float* n_emb  = (const float*)d_in[0];
    const float* h_adj  = (const float*)d_in[1];
    const float* r_adj  = (const float*)d_in[2];
    const float* t_adj  = (const float*)d_in[3];
    const float* mask_r = (const float*)d_in[4];
    const float* mask_u = (const float*)d_in[5];
    const float* Wq     = (const float*)d_in[6];
    const float* Wk     = (const float*)d_in[7];
    float* out = (float*)d_out;

    float* ws  = (float*)d_ws;
    float* Qw  = ws;                        // B*N*E = 65536 floats
    float* Kw  = ws + Bb * Nn * Ee;         // 65536 floats
    float* ori = ws + 2 * Bb * Nn * Ee;     // B*N*N = 262144 floats

    qk_proj<<<Bb * Nn, 64, 0, stream>>>(n_emb, Wq, Wk, Qw, Kw);
    ori_kernel<<<Bb * Nn, 256, 0, stream>>>(Qw, Kw, ori);
    raa_kernel<<<Bb * Rr * Nn, 256, 0, stream>>>(h_adj, r_adj, t_adj,
                                                 mask_r, mask_u, ori, out);
}

// Round 5
// 144.511 us; speedup vs baseline: 1.8184x; 1.1829x over previous
//
#include <hip/hip_runtime.h>
#include <math.h>

#define Bb 4
#define Rr 4
#define Nn 256
#define Ee 64
#define LAMDA 0.5f
#define EPSf 1e-6f

typedef float floatx4 __attribute__((ext_vector_type(4)));

// ---------------- K1: Q = n_emb @ Wq.T, K = n_emb @ Wk.T ----------------
__global__ __launch_bounds__(64) void qk_proj(
    const float* __restrict__ n_emb, const float* __restrict__ Wq,
    const float* __restrict__ Wk, float* __restrict__ Qo, float* __restrict__ Ko)
{
    int bn = blockIdx.x;        // b*N + n
    int e  = threadIdx.x;       // 0..63
    __shared__ float nrow[Ee];
    nrow[e] = n_emb[bn * Ee + e];
    __syncthreads();
    const float* wq = Wq + e * Ee;
    const float* wk = Wk + e * Ee;
    float q = 0.f, k = 0.f;
#pragma unroll
    for (int f = 0; f < Ee; ++f) {
        float nv = nrow[f];
        q += nv * wq[f];
        k += nv * wk[f];
    }
    Qo[bn * Ee + e] = q;
    Ko[bn * Ee + e] = k;
}

// ---------------- K2: ori[b,q,k] = dot(Q[b,q], K[b,k]) / 4096 ----------------
__global__ __launch_bounds__(256) void ori_kernel(
    const float* __restrict__ Q, const float* __restrict__ K,
    float* __restrict__ ori)
{
    int b = blockIdx.x / Nn;
    int q = blockIdx.x % Nn;
    int k = threadIdx.x;        // 0..255
    __shared__ float4 qs[Ee / 4];
    if (k < Ee / 4) qs[k] = ((const float4*)(Q + (b * Nn + q) * Ee))[k];
    __syncthreads();
    const float4* kp = (const float4*)(K + (b * Nn + k) * Ee);
    float acc = 0.f;
#pragma unroll
    for (int u = 0; u < Ee / 4; ++u) {
        float4 kv = kp[u];
        float4 qv = qs[u];
        acc += qv.x * kv.x + qv.y * kv.y + qv.z * kv.z + qv.w * kv.w;
    }
    ori[(b * Nn + q) * Nn + k] = acc * (1.0f / 4096.0f);
}

// ---------------- block-wide sum over 256 threads ----------------
__device__ __forceinline__ float block_sum256(float v, float* s_red) {
#pragma unroll
    for (int m = 32; m >= 1; m >>= 1) v += __shfl_xor(v, m);
    int wid  = threadIdx.x >> 6;
    int lane = threadIdx.x & 63;
    if (lane == 0) s_red[wid] = v;
    __syncthreads();
    float tot = s_red[0] + s_red[1] + s_red[2] + s_red[3];
    __syncthreads();
    return tot;
}

// ---------------- K3: the heavy fused kernel ----------------
// One block per (b, r, i) row: 4096 blocks x 256 threads.
// R2 body (coalesced 1KB/wave loads, in-loop 16-lane shfl reduce, VGPR~16
// -> full residency) + NON-TEMPORAL loads on the three 256MB streams:
// h/r/t are touched exactly once per pass, so L3 retention only steals
// hit-path bandwidth from the masks/ori that DO get reused. nt streams
// them with early-evict hints; masks/ori stay normally cached.
__global__ __launch_bounds__(256) void raa_kernel(
    const float* __restrict__ h_adj, const float* __restrict__ r_adj,
    const float* __restrict__ t_adj, const float* __restrict__ mask_r,
    const float* __restrict__ mask_u, const float* __restrict__ ori,
    float* __restrict__ out)
{
    const int blk = blockIdx.x;            // (b*R + r)*N + i
    const int b   = blk / (Rr * Nn);
    const int i   = blk % Nn;
    const int t   = threadIdx.x;

    const int rowbase4 = blk * (Nn * Ee / 4);   // float4 index, < 2^24
    const floatx4* __restrict__ hp = (const floatx4*)h_adj + rowbase4;
    const floatx4* __restrict__ rp = (const floatx4*)r_adj + rowbase4;
    const floatx4* __restrict__ tp = (const floatx4*)t_adj + rowbase4;

    // Hoist phase-2 loads: independent of phase 1, latency hides under it.
    const int j     = t;
    const int mbase = blk * Nn;
    const float mr  = mask_r[mbase + j];
    const float mu  = mask_u[mbase + j];
    const float o   = ori[(b * Nn + i) * Nn + j];

    __shared__ float s_pla[Nn];
    __shared__ float s_red[4];

    // Phase 1: pla_scores[j] = || h + r - t ||_2 over E=64.
    // Step v: thread t reads float4 #(v*256+t) -> wave covers 1KB contiguous.
    // That float4 belongs to column jcol = v*16 + (t>>4): 16-lane shfl tree.
#pragma unroll
    for (int v = 0; v < 16; ++v) {
        int idx = v * 256 + t;
        floatx4 hv = __builtin_nontemporal_load(hp + idx);
        floatx4 rv = __builtin_nontemporal_load(rp + idx);
        floatx4 tv = __builtin_nontemporal_load(tp + idx);
        float dx = hv[0] + rv[0] - tv[0];
        float dy = hv[1] + rv[1] - tv[1];
        float dz = hv[2] + rv[2] - tv[2];
        float dw = hv[3] + rv[3] - tv[3];
        float acc = dx * dx + dy * dy + dz * dz + dw * dw;
        acc += __shfl_xor(acc, 1);
        acc += __shfl_xor(acc, 2);
        acc += __shfl_xor(acc, 4);
        acc += __shfl_xor(acc, 8);
        if ((t & 15) == 0) s_pla[v * 16 + (t >> 4)] = sqrtf(acc);
    }
    __syncthreads();

    // Phase 2: masked softmax-ish chain, thread j owns column j
    float e1 = expf(-s_pla[j]) * mr;
    float s1 = block_sum256(e1, s_red);
    float w  = e1 / (s1 + EPSf);

    float raa = o * (1.0f + LAMDA * w);

    float e2 = expf(raa) * mu;
    float s2 = block_sum256(e2, s_red);

    out[mbase + j] = e2 / (s2 + EPSf);
}

extern "C" void kernel_launch(void* const* d_in, const int* in_sizes, int n_in,
                              void* d_out, int out_size, void* d_ws, size_t ws_size,
                              hipStream_t stream) {
    const float* n_emb  = (const float*)d_in[0];
    const float* h_adj  = (const float*)d_in[1];
    const float* r_adj  = (const float*)d_in[2];
    const float* t_adj  = (const float*)d_in[3];
    const float* mask_r = (const float*)d_in[4];
    const float* mask_u = (const float*)d_in[5];
    const float* Wq     = (const float*)d_in[6];
    const float* Wk     = (const float*)d_in[7];
    float* out = (float*)d_out;

    float* ws  = (float*)d_ws;
    float* Qw  = ws;                        // B*N*E = 65536 floats
    float* Kw  = ws + Bb * Nn * Ee;         // 65536 floats
    float* ori = ws + 2 * Bb * Nn * Ee;     // B*N*N = 262144 floats

    qk_proj<<<Bb * Nn, 64, 0, stream>>>(n_emb, Wq, Wk, Qw, Kw);
    ori_kernel<<<Bb * Nn, 256, 0, stream>>>(Qw, Kw, ori);
    raa_kernel<<<Bb * Rr * Nn, 256, 0, stream>>>(h_adj, r_adj, t_adj,
                                                 mask_r, mask_u, ori, out);
}